// Round 15
// baseline (311.495 us; speedup 1.0000x reference)
//
#include <hip/hip_runtime.h>

typedef unsigned long long u64;
typedef int i32x4 __attribute__((ext_vector_type(4)));
typedef int i32x16 __attribute__((ext_vector_type(16)));
typedef short s16x8 __attribute__((ext_vector_type(8)));
typedef float f32x4 __attribute__((ext_vector_type(4)));

#define N_SP 3136          // 56*56
#define C_IN 256
#define C_OUT 256
#define BATCH 32
#define NBLK 1792          // 32 b x 56 output rows (x-dim of conv grid)
// xsignT: [b][hp 0..57][wp stride 64 (0..57 used)][ci 0..255] int8, zero borders
#define XROW 64
#define XPLANE (58 * XROW * 256)          // per-image bytes = 950272
#define XSIZE ((size_t)BATCH * XPLANE)    // 30,408,704 B
#define S16_OFF ((size_t)36 << 20)
#define S16_BYTES ((size_t)BATCH * C_OUT * N_SP * 2)   // 51,380,224

// ---------------------------------------------------------------- weight prep
__global__ __launch_bounds__(256) void prep_weights(const float* __restrict__ w,
                                                    char* __restrict__ A_pack,
                                                    double* __restrict__ alpha) {
    const int o = blockIdx.x;
    const int i = threadIdx.x;           // input channel
    const int lane = i & 63, wvid = i >> 6;
    __shared__ double part[4][9];
    __shared__ double part2[4];

    float wv[9];
    const float* wp = w + ((size_t)o * C_IN + i) * 9;
#pragma unroll
    for (int t = 0; t < 9; ++t) wv[t] = wp[t];

#pragma unroll
    for (int t = 0; t < 9; ++t) {
        double v = (double)wv[t];
#pragma unroll
        for (int off = 32; off > 0; off >>= 1) v += __shfl_down(v, off);
        if (lane == 0) part[wvid][t] = v;
    }
    __syncthreads();

    double asum = 0.0;
#pragma unroll
    for (int t = 0; t < 9; ++t) {
        double mean = (part[0][t] + part[1][t] + part[2][t] + part[3][t]) * (1.0 / 256.0);
        double wc = (double)wv[t] - mean;
        // fragment-order scatter: idx16 = ((t*8 + ci/32)*8 + o/32)*64 + ((ci>>4)&1)*32 + (o&31)
        int idx16 = ((t * 8 + (i >> 5)) * 8 + (o >> 5)) * 64 + (((i >> 4) & 1) << 5) + (o & 31);
        A_pack[(size_t)idx16 * 16 + (i & 15)] = (char)(wc > 0.0 ? 1 : -1);
        double aw = fabs(wc);
        if (aw > 1.0) aw = 1.0;
        asum += aw;
    }
#pragma unroll
    for (int off = 32; off > 0; off >>= 1) asum += __shfl_down(asum, off);
    if (lane == 0) part2[wvid] = asum;
    __syncthreads();
    if (i == 0)
        alpha[o] = (part2[0] + part2[1] + part2[2] + part2[3]) * (1.0 / 2304.0);
}

// ---------------------------------------------------------------- sign transpose
// grid (49, 32). x loads are read-once: non-temporal. Border zeroing folded in.
__global__ __launch_bounds__(256) void sign_transpose(const float* __restrict__ x,
                                                      char* __restrict__ xsT) {
    const int sp0 = blockIdx.x * 64;
    const int b = blockIdx.y;
    const int lane = threadIdx.x & 63;     // sp within tile
    const int wv = threadIdx.x >> 6;       // ci block of 64
    __shared__ char tile[64 * 272];        // [sp][ci], +16 pad

    // ---- border zeroing slice (independent addresses, no sync needed) ----
    {
        const int tidl = (blockIdx.y * 49 + blockIdx.x) * 256 + threadIdx.x;
        if (tidl < 294912) {
            const int bb = tidl / 9216;
            const int r = tidl - bb * 9216;
            int hp, wp, c16;
            if (r < 2048) {                       // full rows 0 and 57
                hp = (r >> 10) * 57;
                wp = (r >> 4) & 63;
                c16 = (r & 15) << 4;
            } else {                              // cols 0, 57..63 of rows 1..56
                int r2 = r - 2048;
                hp = 1 + (r2 >> 7);
                int q = r2 & 127;
                int wi = q >> 4;
                wp = (wi == 0) ? 0 : 56 + wi;
                c16 = (q & 15) << 4;
            }
            *(i32x4*)(xsT + (((size_t)(bb * 58 + hp) << 6) + wp) * 256 + c16) =
                (i32x4){0, 0, 0, 0};
        }
    }

    const float* xp = x + ((size_t)(b * 256 + (wv << 6))) * N_SP + sp0 + lane;
#pragma unroll
    for (int q = 0; q < 4; ++q) {          // 4 × 16 ci -> 4 × b128 LDS writes
        unsigned d[4];
#pragma unroll
        for (int dd = 0; dd < 4; ++dd) {
            unsigned v = 0;
#pragma unroll
            for (int kk = 0; kk < 4; ++kk) {
                int ci_l = (q << 4) + (dd << 2) + kk;
                float xv = __builtin_nontemporal_load(xp + (size_t)ci_l * N_SP);
                v |= (unsigned)(xv > 0.0f ? 0x01u : 0xFFu) << (8 * kk);
            }
            d[dd] = v;
        }
        *(i32x4*)(tile + lane * 272 + (wv << 6) + (q << 4)) =
            (i32x4){(int)d[0], (int)d[1], (int)d[2], (int)d[3]};
    }
    __syncthreads();

    const int t = threadIdx.x;
#pragma unroll
    for (int j = 0; j < 4; ++j) {
        int sp_loc = (j << 4) + (t >> 4);
        int ci0 = (t & 15) << 4;
        i32x4 v = *(const i32x4*)(tile + sp_loc * 272 + ci0);
        int spg = sp0 + sp_loc;
        int h = spg / 56, w = spg - h * 56;
        size_t dst = (((size_t)(b * 58 + h + 1) << 6) + (w + 1)) * 256 + ci0;
        *(i32x4*)(xsT + dst) = v;
    }
}

// ---------------------------------------------------------------- MFMA conv
// grid (1792), block 512 = 8 waves (R9 geometry - proven best at 99 us).
// Wave wv owns ONE 32-co block (co5 = wv): acc[2] = [nh], 32 acc VGPRs.
// R22/R23/R24 (R13 container died twice, R14 GPU-acquisition timeout -
// identical resubmit #2): INLINE-ASM per-tap A-batch. R12's source-level
// batch was nulled (VGPR stayed 40 - compiler re-sank the loads; 3rd such
// deletion: R2 ring, R12 batch). asm volatile global_load_dwordx4 with
// "=&v" outputs is opaque to the scheduler and CANNOT be re-sunk: the 8
// loads of a tap issue back-to-back, ONE s_waitcnt vmcnt(0) +
// sched_barrier(0) (rule #18: asm outputs get no auto-waitcnt; MFMAs must
// not hoist above the wait), then 8 MFMA pairs consume. A-load latency
// (~220 cyc L2) amortizes 8x -> ~27 cyc/iter vs 220 today; predicted
// period 356 -> ~150-180 cyc. VGPR tell: 40 -> ~85 (a8 materialized).
// In-loop vmcnt(0) is safe: no other vm ops in flight inside the K-loop
// (staging drained at barrier; stores are after the loop).
// S stored int16 (|S| <= 2304), NT (R4-R12-verified, absmax 0).
// Fragment layouts (verified R6-R9, absmax 0): A/B m|n=lane&31, k=(lane>>5)*16+j;
// C/D col=lane&31, row=(reg&3)+8*(reg>>2)+4*(lane>>5).
__global__ __launch_bounds__(512, 4) void conv_mfma(const char* __restrict__ xsT,
                                                    const char* __restrict__ A_pack,
                                                    float* __restrict__ out,
                                                    short* __restrict__ s16,
                                                    int2* __restrict__ partials) {
    const int tid = threadIdx.x;
    const int lane = tid & 63;
    const int wv = tid >> 6;              // wave -> 32-channel block (co5 = wv)
    const int l31 = lane & 31, l5 = lane >> 5;
    const int blk = blockIdx.x;
    const int b = blk / 56;
    const int h0 = blk - b * 56;          // output row

    __shared__ char slab[3 * 58 * 272];   // [dh 0..2][wp 0..57][ci], ci padded to 272

    // stage 3 source rows (padded h0..h0+2) of 58 wp x 256 ci
    {
        const char* src = xsT + ((size_t)(b * 58 + h0) << 6) * 256;
        for (int c = tid; c < 3 * 58 * 16; c += 512) {       // 16B chunks
            int dh = c / (58 * 16);
            int rem = c - dh * (58 * 16);
            int wp = rem >> 4, c16 = (rem & 15) << 4;
            *(i32x4*)(slab + (dh * 58 + wp) * 272 + c16) =
                *(const i32x4*)(src + (size_t)dh * (XROW * 256) + wp * 256 + c16);
        }
    }
    __syncthreads();

    i32x16 acc[2] = {};   // [nh]

    // per-lane base pointers (computed once)
    const char* apb = A_pack + (size_t)(wv * 1024) + lane * 16;      // +it*8192
    const char* sb0 = slab + l31 * 272 + l5 * 16;                    // +((dh*58+dw)*272 + cib*32)
    // b1 bases per dw with garbage-lane clamp folded in (border col 57 = zeros)
    int w1_0 = 32 + l31;     if (w1_0 > 57) w1_0 = 57;
    int w1_1 = 33 + l31;     if (w1_1 > 57) w1_1 = 57;
    int w1_2 = 34 + l31;     if (w1_2 > 57) w1_2 = 57;
    const char* sb1_0 = slab + w1_0 * 272 + l5 * 16;                 // +(dh*58*272 + cib*32)
    const char* sb1_1 = slab + w1_1 * 272 + l5 * 16;
    const char* sb1_2 = slab + w1_2 * 272 + l5 * 16;

#pragma unroll
    for (int tap = 0; tap < 9; ++tap) {
        const int dh = tap / 3, dw = tap - 3 * (tap / 3);
        const char* sb1 = (dw == 0) ? sb1_0 : ((dw == 1) ? sb1_1 : sb1_2);

        // ---- asm-pinned batch: 8 independent A-loads issue back-to-back ----
        i32x4 a8[8];
#pragma unroll
        for (int cib = 0; cib < 8; ++cib) {
            const char* ga = apb + (size_t)(tap * 8 + cib) * 8192;
            asm volatile("global_load_dwordx4 %0, %1, off"
                         : "=&v"(a8[cib]) : "v"(ga) : "memory");
        }
        asm volatile("s_waitcnt vmcnt(0)" ::: "memory");
        __builtin_amdgcn_sched_barrier(0);

#pragma unroll
        for (int cib = 0; cib < 8; ++cib) {
            i32x4 b0 = *(const i32x4*)(sb0 + (dh * 58 + dw) * 272 + cib * 32);
            i32x4 b1 = *(const i32x4*)(sb1 + dh * 58 * 272 + cib * 32);
            acc[0] = __builtin_amdgcn_mfma_i32_32x32x32_i8(a8[cib], b0, acc[0], 0, 0, 0);
            acc[1] = __builtin_amdgcn_mfma_i32_32x32x32_i8(a8[cib], b1, acc[1], 0, 0, 0);
        }
    }

    // ---- stores: S exact integer, non-temporal ----
    if (s16) {
        short* sb = s16 + ((size_t)(b * 256 + wv * 32)) * N_SP + h0 * 56;
#pragma unroll
        for (int nh = 0; nh < 2; ++nh) {
            const int w = nh * 32 + l31;
            if (w < 56) {
#pragma unroll
                for (int reg = 0; reg < 16; ++reg) {
                    int corow = (reg & 3) + 8 * (reg >> 2) + 4 * l5;
                    __builtin_nontemporal_store(
                        (short)acc[nh][reg],
                        sb + (size_t)corow * N_SP + w);
                }
            }
        }
    } else {
        float* ob = out + ((size_t)(b * 256 + wv * 32)) * N_SP + h0 * 56;
#pragma unroll
        for (int nh = 0; nh < 2; ++nh) {
            const int w = nh * 32 + l31;
            if (w < 56) {
#pragma unroll
                for (int reg = 0; reg < 16; ++reg) {
                    int corow = (reg & 3) + 8 * (reg >> 2) + 4 * l5;
                    __builtin_nontemporal_store(
                        (float)acc[nh][reg],
                        ob + (size_t)corow * N_SP + w);
                }
            }
        }
    }

    // ---- per-block channel stats partials (no atomics) ----
    __syncthreads();                       // all waves done reading slab
    int* sp_s = (int*)slab;                // [256]
    int* sp_q = (int*)slab + 256;          // [256]
#pragma unroll
    for (int reg = 0; reg < 16; ++reg) {
        int v0 = acc[0][reg];
        int v1 = (l31 < 24) ? acc[1][reg] : 0;
        int s = v0 + v1;
        unsigned q = (unsigned)(v0 * v0) + (unsigned)(v1 * v1);
#pragma unroll
        for (int off = 16; off > 0; off >>= 1) {   // reduce within 32-lane half
            s += __shfl_xor(s, off);
            q += (unsigned)__shfl_xor((int)q, off);
        }
        if (l31 == 0) {
            int corow = (reg & 3) + 8 * (reg >> 2) + 4 * l5;
            sp_s[wv * 32 + corow] = s;
            sp_q[wv * 32 + corow] = (int)q;
        }
    }
    __syncthreads();
    if (tid < 256) {
        u64 v = (u64)(unsigned)sp_s[tid] | ((u64)(unsigned)sp_q[tid] << 32);
        __builtin_nontemporal_store(v, (u64*)(partials + (size_t)tid * NBLK + blk));
    }
}

// ---------------------------------------------------------------- stats+consts
__global__ __launch_bounds__(256) void stats_consts(const int2* __restrict__ partials,
                                                    const double* __restrict__ alpha,
                                                    const float* __restrict__ gamma,
                                                    const float* __restrict__ beta,
                                                    double* __restrict__ AB) {
    const int c = blockIdx.x;
    const int t = threadIdx.x;
    long long s1 = 0, s2 = 0;
    for (int blk = t; blk < NBLK; blk += 256) {
        int2 v = partials[(size_t)c * NBLK + blk];
        s1 += v.x;
        s2 += (long long)(unsigned)v.y;
    }
#pragma unroll
    for (int off = 32; off > 0; off >>= 1) {
        s1 += __shfl_down(s1, off);
        s2 += __shfl_down(s2, off);
    }
    __shared__ long long p1[4], p2[4];
    if ((t & 63) == 0) { p1[t >> 6] = s1; p2[t >> 6] = s2; }
    __syncthreads();
    if (t == 0) {
        double S1 = (double)(p1[0] + p1[1] + p1[2] + p1[3]);
        double S2 = (double)(p2[0] + p2[1] + p2[2] + p2[3]);
        const double N = (double)(BATCH * N_SP);
        double mu = S1 / N;
        double var = S2 / N - mu * mu;
        double a = alpha[c];
        double vy = a * a * var;
        double scale = (double)gamma[c] / sqrt(vy + 1e-5);
        double A = a * scale;
        double B = (double)beta[c] - A * mu;
        AB[c] = A;
        AB[C_OUT + c] = B;
    }
}

// ---------------------------------------------------------------- finalize (float in-place)
__global__ __launch_bounds__(256) void finalize(float* __restrict__ out,
                                                const double* __restrict__ AB) {
    const unsigned i4 = blockIdx.x * 256 + threadIdx.x;   // 0 .. 6422527
    const unsigned e = i4 << 2;                            // element base
    const int c = (int)((e / N_SP) & (C_OUT - 1));         // 3136 | 4 -> c uniform in float4
    const double A = AB[c];
    const double B = AB[C_OUT + c];
    float4 v = ((float4*)out)[i4];
    v.x = (A * (double)v.x + B) > 0.0 ? 1.0f : 0.0f;
    v.y = (A * (double)v.y + B) > 0.0 ? 1.0f : 0.0f;
    v.z = (A * (double)v.z + B) > 0.0 ? 1.0f : 0.0f;
    v.w = (A * (double)v.w + B) > 0.0 ? 1.0f : 0.0f;
    ((float4*)out)[i4] = v;
}

// ---------------------------------------------------------------- finalize16
// Reads int16 S (16B/thread, NT), writes float 0/1 (32B/thread, NT).
__global__ __launch_bounds__(256) void finalize16(const short* __restrict__ S,
                                                  float* __restrict__ out,
                                                  const double* __restrict__ AB) {
    const unsigned t = blockIdx.x * 256 + threadIdx.x;    // 0 .. 3,211,263
    const unsigned e = t << 3;                             // element base, 8 per thread
    const int c = (int)((e / N_SP) & (C_OUT - 1));         // 3136 | 8 -> c uniform per chunk
    const double A = AB[c];
    const double B = AB[C_OUT + c];
    s16x8 v = __builtin_nontemporal_load((const s16x8*)(S + e));
    f32x4 o0, o1;
    o0.x = (A * (double)v[0] + B) > 0.0 ? 1.0f : 0.0f;
    o0.y = (A * (double)v[1] + B) > 0.0 ? 1.0f : 0.0f;
    o0.z = (A * (double)v[2] + B) > 0.0 ? 1.0f : 0.0f;
    o0.w = (A * (double)v[3] + B) > 0.0 ? 1.0f : 0.0f;
    o1.x = (A * (double)v[4] + B) > 0.0 ? 1.0f : 0.0f;
    o1.y = (A * (double)v[5] + B) > 0.0 ? 1.0f : 0.0f;
    o1.z = (A * (double)v[6] + B) > 0.0 ? 1.0f : 0.0f;
    o1.w = (A * (double)v[7] + B) > 0.0 ? 1.0f : 0.0f;
    __builtin_nontemporal_store(o0, (f32x4*)(out + e));
    __builtin_nontemporal_store(o1, (f32x4*)(out + e + 4));
}

// ---------------------------------------------------------------- launch
extern "C" void kernel_launch(void* const* d_in, const int* in_sizes, int n_in,
                              void* d_out, int out_size, void* d_ws, size_t ws_size,
                              hipStream_t stream) {
    const float* x      = (const float*)d_in[0];
    const float* weight = (const float*)d_in[1];
    const float* bias   = (const float*)d_in[2];   (void)bias;  // cancels in BN
    const float* gamma  = (const float*)d_in[3];
    const float* beta   = (const float*)d_in[4];
    float* out = (float*)d_out;

    char* ws = (char*)d_ws;
    double* alpha = (double*)(ws + 4096);       // [256]
    double* AB    = (double*)(ws + 8192);       // [512]
    char*   A_pack = (char*)(ws + 16384);       // 589,824 B fragment-ordered signs
    int2*   partials = (int2*)(ws + (1 << 20)); // 256*1792*8 = 3.67 MB (ends < 5 MB)
    char*   xsT   = (char*)(ws + (5 << 20));    // 30,408,704 B -> ends < 36 MB
    const bool use16 = ws_size >= S16_OFF + S16_BYTES;
    short*  s16 = use16 ? (short*)(ws + S16_OFF) : (short*)0;   // 51,380,224 B

    prep_weights<<<C_OUT, 256, 0, stream>>>(weight, A_pack, alpha);
    sign_transpose<<<dim3(49, BATCH), 256, 0, stream>>>(x, xsT);
    conv_mfma<<<dim3(NBLK), 512, 0, stream>>>(xsT, A_pack, out, s16, partials);
    stats_consts<<<C_OUT, 256, 0, stream>>>(partials, alpha, gamma, beta, AB);
    if (use16)
        finalize16<<<12544, 256, 0, stream>>>(s16, out, AB);
    else
        finalize<<<(out_size / 4) / 256, 256, 0, stream>>>(out, AB);
}

// Round 16
// 302.106 us; speedup vs baseline: 1.0311x; 1.0311x over previous
//
#include <hip/hip_runtime.h>

typedef unsigned long long u64;
typedef int i32x4 __attribute__((ext_vector_type(4)));
typedef int i32x16 __attribute__((ext_vector_type(16)));
typedef short s16x8 __attribute__((ext_vector_type(8)));
typedef float f32x4 __attribute__((ext_vector_type(4)));

#define N_SP 3136          // 56*56
#define C_IN 256
#define C_OUT 256
#define BATCH 32
#define NBLK 1792          // 32 b x 56 output rows (x-dim of conv grid)
// xsignT: [b][hp 0..57][wp stride 64 (0..57 used)][ci 0..255] int8, zero borders
#define XROW 64
#define XPLANE (58 * XROW * 256)          // per-image bytes = 950272
#define XSIZE ((size_t)BATCH * XPLANE)    // 30,408,704 B
#define S16_OFF ((size_t)36 << 20)
#define S16_BYTES ((size_t)BATCH * C_OUT * N_SP * 2)   // 51,380,224

// ---------------------------------------------------------------- prep + sign transpose (merged)
// R25: conv reverted to R9 keeper (R15 refuted load-batching: asm-pinned
// batch held in regs, VGPR 48, yet conv 99.6->103 us - A-path is
// throughput-limited per wave, not latency; occupancy/prefetch/batch all
// exhausted). Pivot to the ~205 us non-conv budget (constant R0-R12;
// memory floor ~40 us). This kernel: (a) sign_transpose rewritten with
// FLOAT4 x-loads (was scalar 4B - G13 violation; 4x fewer load instrs,
// 16B/lane); thread (wv,cg,sq) packs 4 sp x 16 ci; (b) prep_weights
// merged as blocks 1568..1823 (one fewer launch).
__global__ __launch_bounds__(256) void prep_and_transpose(const float* __restrict__ x,
                                                          char* __restrict__ xsT,
                                                          const float* __restrict__ w,
                                                          char* __restrict__ A_pack,
                                                          double* __restrict__ alpha) {
    const int bid = blockIdx.x;
    const int t = threadIdx.x;

    if (bid >= 1568) {
        // ---------------- weight prep (one block per output channel) ----------------
        const int o = bid - 1568;
        const int i = t;                    // input channel
        const int lane = i & 63, wvid = i >> 6;
        __shared__ double part[4][9];
        __shared__ double part2[4];

        float wv[9];
        const float* wp = w + ((size_t)o * C_IN + i) * 9;
#pragma unroll
        for (int tt = 0; tt < 9; ++tt) wv[tt] = wp[tt];

#pragma unroll
        for (int tt = 0; tt < 9; ++tt) {
            double v = (double)wv[tt];
#pragma unroll
            for (int off = 32; off > 0; off >>= 1) v += __shfl_down(v, off);
            if (lane == 0) part[wvid][tt] = v;
        }
        __syncthreads();

        double asum = 0.0;
#pragma unroll
        for (int tt = 0; tt < 9; ++tt) {
            double mean = (part[0][tt] + part[1][tt] + part[2][tt] + part[3][tt]) * (1.0 / 256.0);
            double wc = (double)wv[tt] - mean;
            // fragment-order scatter: idx16 = ((t*8 + ci/32)*8 + o/32)*64 + ((ci>>4)&1)*32 + (o&31)
            int idx16 = ((tt * 8 + (i >> 5)) * 8 + (o >> 5)) * 64 + (((i >> 4) & 1) << 5) + (o & 31);
            A_pack[(size_t)idx16 * 16 + (i & 15)] = (char)(wc > 0.0 ? 1 : -1);
            double aw = fabs(wc);
            if (aw > 1.0) aw = 1.0;
            asum += aw;
        }
#pragma unroll
        for (int off = 32; off > 0; off >>= 1) asum += __shfl_down(asum, off);
        if (lane == 0) part2[wvid] = asum;
        __syncthreads();
        if (i == 0)
            alpha[o] = (part2[0] + part2[1] + part2[2] + part2[3]) * (1.0 / 2304.0);
        return;
    }

    // ---------------- sign transpose: block = (b = bid/49, sp-tile = bid%49) ----------------
    const int b = bid / 49;
    const int sp0 = (bid - b * 49) * 64;
    __shared__ char tile[64 * 272];        // [sp][ci], +16 pad

    // ---- border zeroing slice (independent addresses, no sync needed) ----
    {
        const int tidl = bid * 256 + t;
        if (tidl < 294912) {
            const int bb = tidl / 9216;
            const int r = tidl - bb * 9216;
            int hp, wp2, c16;
            if (r < 2048) {                       // full rows 0 and 57
                hp = (r >> 10) * 57;
                wp2 = (r >> 4) & 63;
                c16 = (r & 15) << 4;
            } else {                              // cols 0, 57..63 of rows 1..56
                int r2 = r - 2048;
                hp = 1 + (r2 >> 7);
                int q = r2 & 127;
                int wi = q >> 4;
                wp2 = (wi == 0) ? 0 : 56 + wi;
                c16 = (q & 15) << 4;
            }
            *(i32x4*)(xsT + (((size_t)(bb * 58 + hp) << 6) + wp2) * 256 + c16) =
                (i32x4){0, 0, 0, 0};
        }
    }

    // ---- float4 loads: thread (wv = ci-block of 64, cg = 16-ci group, sq = sp quad) ----
    const int wv = t >> 6;                 // 0..3
    const int lane = t & 63;
    const int sq = lane & 15;              // sp quad: sp_loc = sq*4 .. +3
    const int cg = lane >> 4;              // 0..3: ci sub-base = cg*16
    const int ci0t = wv * 64 + cg * 16;

    unsigned d[4][4];                      // [j = sp within quad][word]
#pragma unroll
    for (int j = 0; j < 4; ++j)
#pragma unroll
        for (int ww = 0; ww < 4; ++ww) d[j][ww] = 0;

    const float* xp = x + ((size_t)(b * 256 + ci0t)) * N_SP + sp0 + sq * 4;
#pragma unroll
    for (int k = 0; k < 16; ++k) {
        f32x4 v = __builtin_nontemporal_load((const f32x4*)(xp + (size_t)k * N_SP));
        const int ww = k >> 2, sh = (k & 3) * 8;
        d[0][ww] |= (v[0] > 0.0f ? 0x01u : 0xFFu) << sh;
        d[1][ww] |= (v[1] > 0.0f ? 0x01u : 0xFFu) << sh;
        d[2][ww] |= (v[2] > 0.0f ? 0x01u : 0xFFu) << sh;
        d[3][ww] |= (v[3] > 0.0f ? 0x01u : 0xFFu) << sh;
    }
#pragma unroll
    for (int j = 0; j < 4; ++j) {
        *(i32x4*)(tile + (sq * 4 + j) * 272 + ci0t) =
            (i32x4){(int)d[j][0], (int)d[j][1], (int)d[j][2], (int)d[j][3]};
    }
    __syncthreads();

    // ---- output: 16B ci chunks, channel-last padded layout ----
#pragma unroll
    for (int j = 0; j < 4; ++j) {
        int sp_loc = (j << 4) + (t >> 4);
        int ci0 = (t & 15) << 4;
        i32x4 v = *(const i32x4*)(tile + sp_loc * 272 + ci0);
        int spg = sp0 + sp_loc;
        int h = spg / 56, w2 = spg - h * 56;
        size_t dst = (((size_t)(b * 58 + h + 1) << 6) + (w2 + 1)) * 256 + ci0;
        *(i32x4*)(xsT + dst) = v;
    }
}

// ---------------------------------------------------------------- MFMA conv
// grid (1792), block 512 = 8 waves. R9 KEEPER (proven best: conv ~99 us,
// VGPR 40, 24 waves/CU). Wave wv owns ONE 32-co block (co5 = wv):
// acc[2] = [nh], 32 acc VGPRs. Per-wave service rate is the floor
// (R8/R11/R12/R15: prefetch rings, 32-wave cap, source batch, asm batch
// all null or regressed).
// S stored int16 (|S| <= 2304), NT (R4-R15-verified, absmax 0).
// Fragment layouts (verified R6-R9, absmax 0): A/B m|n=lane&31, k=(lane>>5)*16+j;
// C/D col=lane&31, row=(reg&3)+8*(reg>>2)+4*(lane>>5).
__global__ __launch_bounds__(512, 4) void conv_mfma(const char* __restrict__ xsT,
                                                    const char* __restrict__ A_pack,
                                                    float* __restrict__ out,
                                                    short* __restrict__ s16,
                                                    int2* __restrict__ partials) {
    const int tid = threadIdx.x;
    const int lane = tid & 63;
    const int wv = tid >> 6;              // wave -> 32-channel block (co5 = wv)
    const int l31 = lane & 31, l5 = lane >> 5;
    const int blk = blockIdx.x;
    const int b = blk / 56;
    const int h0 = blk - b * 56;          // output row

    __shared__ char slab[3 * 58 * 272];   // [dh 0..2][wp 0..57][ci], ci padded to 272

    // stage 3 source rows (padded h0..h0+2) of 58 wp x 256 ci
    {
        const char* src = xsT + ((size_t)(b * 58 + h0) << 6) * 256;
        for (int c = tid; c < 3 * 58 * 16; c += 512) {       // 16B chunks
            int dh = c / (58 * 16);
            int rem = c - dh * (58 * 16);
            int wp = rem >> 4, c16 = (rem & 15) << 4;
            *(i32x4*)(slab + (dh * 58 + wp) * 272 + c16) =
                *(const i32x4*)(src + (size_t)dh * (XROW * 256) + wp * 256 + c16);
        }
    }
    __syncthreads();

    i32x16 acc[2] = {};   // [nh]

    // per-lane base pointers (computed once)
    const char* apb = A_pack + (size_t)(wv * 1024) + lane * 16;      // +it*8192
    const char* sb0 = slab + l31 * 272 + l5 * 16;                    // +((dh*58+dw)*272 + cib*32)
    // b1 bases per dw with garbage-lane clamp folded in (border col 57 = zeros)
    int w1_0 = 32 + l31;     if (w1_0 > 57) w1_0 = 57;
    int w1_1 = 33 + l31;     if (w1_1 > 57) w1_1 = 57;
    int w1_2 = 34 + l31;     if (w1_2 > 57) w1_2 = 57;
    const char* sb1_0 = slab + w1_0 * 272 + l5 * 16;                 // +(dh*58*272 + cib*32)
    const char* sb1_1 = slab + w1_1 * 272 + l5 * 16;
    const char* sb1_2 = slab + w1_2 * 272 + l5 * 16;

#pragma unroll
    for (int tap = 0; tap < 9; ++tap) {
        const int dh = tap / 3, dw = tap - 3 * (tap / 3);
        const char* sb1 = (dw == 0) ? sb1_0 : ((dw == 1) ? sb1_1 : sb1_2);
#pragma unroll
        for (int cib = 0; cib < 8; ++cib) {
            const int it = tap * 8 + cib;
            i32x4 a = *(const i32x4*)(apb + (size_t)it * 8192);
            i32x4 b0 = *(const i32x4*)(sb0 + (dh * 58 + dw) * 272 + cib * 32);
            i32x4 b1 = *(const i32x4*)(sb1 + dh * 58 * 272 + cib * 32);
            acc[0] = __builtin_amdgcn_mfma_i32_32x32x32_i8(a, b0, acc[0], 0, 0, 0);
            acc[1] = __builtin_amdgcn_mfma_i32_32x32x32_i8(a, b1, acc[1], 0, 0, 0);
        }
    }

    // ---- stores: S exact integer, non-temporal ----
    if (s16) {
        short* sb = s16 + ((size_t)(b * 256 + wv * 32)) * N_SP + h0 * 56;
#pragma unroll
        for (int nh = 0; nh < 2; ++nh) {
            const int w = nh * 32 + l31;
            if (w < 56) {
#pragma unroll
                for (int reg = 0; reg < 16; ++reg) {
                    int corow = (reg & 3) + 8 * (reg >> 2) + 4 * l5;
                    __builtin_nontemporal_store(
                        (short)acc[nh][reg],
                        sb + (size_t)corow * N_SP + w);
                }
            }
        }
    } else {
        float* ob = out + ((size_t)(b * 256 + wv * 32)) * N_SP + h0 * 56;
#pragma unroll
        for (int nh = 0; nh < 2; ++nh) {
            const int w = nh * 32 + l31;
            if (w < 56) {
#pragma unroll
                for (int reg = 0; reg < 16; ++reg) {
                    int corow = (reg & 3) + 8 * (reg >> 2) + 4 * l5;
                    __builtin_nontemporal_store(
                        (float)acc[nh][reg],
                        ob + (size_t)corow * N_SP + w);
                }
            }
        }
    }

    // ---- per-block channel stats partials (no atomics) ----
    __syncthreads();                       // all waves done reading slab
    int* sp_s = (int*)slab;                // [256]
    int* sp_q = (int*)slab + 256;          // [256]
#pragma unroll
    for (int reg = 0; reg < 16; ++reg) {
        int v0 = acc[0][reg];
        int v1 = (l31 < 24) ? acc[1][reg] : 0;
        int s = v0 + v1;
        unsigned q = (unsigned)(v0 * v0) + (unsigned)(v1 * v1);
#pragma unroll
        for (int off = 16; off > 0; off >>= 1) {   // reduce within 32-lane half
            s += __shfl_xor(s, off);
            q += (unsigned)__shfl_xor((int)q, off);
        }
        if (l31 == 0) {
            int corow = (reg & 3) + 8 * (reg >> 2) + 4 * l5;
            sp_s[wv * 32 + corow] = s;
            sp_q[wv * 32 + corow] = (int)q;
        }
    }
    __syncthreads();
    if (tid < 256) {
        u64 v = (u64)(unsigned)sp_s[tid] | ((u64)(unsigned)sp_q[tid] << 32);
        __builtin_nontemporal_store(v, (u64*)(partials + (size_t)tid * NBLK + blk));
    }
}

// ---------------------------------------------------------------- stats+consts
__global__ __launch_bounds__(256) void stats_consts(const int2* __restrict__ partials,
                                                    const double* __restrict__ alpha,
                                                    const float* __restrict__ gamma,
                                                    const float* __restrict__ beta,
                                                    double* __restrict__ AB) {
    const int c = blockIdx.x;
    const int t = threadIdx.x;
    long long s1 = 0, s2 = 0;
    for (int blk = t; blk < NBLK; blk += 256) {
        int2 v = partials[(size_t)c * NBLK + blk];
        s1 += v.x;
        s2 += (long long)(unsigned)v.y;
    }
#pragma unroll
    for (int off = 32; off > 0; off >>= 1) {
        s1 += __shfl_down(s1, off);
        s2 += __shfl_down(s2, off);
    }
    __shared__ long long p1[4], p2[4];
    if ((t & 63) == 0) { p1[t >> 6] = s1; p2[t >> 6] = s2; }
    __syncthreads();
    if (t == 0) {
        double S1 = (double)(p1[0] + p1[1] + p1[2] + p1[3]);
        double S2 = (double)(p2[0] + p2[1] + p2[2] + p2[3]);
        const double N = (double)(BATCH * N_SP);
        double mu = S1 / N;
        double var = S2 / N - mu * mu;
        double a = alpha[c];
        double vy = a * a * var;
        double scale = (double)gamma[c] / sqrt(vy + 1e-5);
        double A = a * scale;
        double B = (double)beta[c] - A * mu;
        AB[c] = A;
        AB[C_OUT + c] = B;
    }
}

// ---------------------------------------------------------------- finalize (float in-place)
__global__ __launch_bounds__(256) void finalize(float* __restrict__ out,
                                                const double* __restrict__ AB) {
    const unsigned i4 = blockIdx.x * 256 + threadIdx.x;   // 0 .. 6422527
    const unsigned e = i4 << 2;                            // element base
    const int c = (int)((e / N_SP) & (C_OUT - 1));         // 3136 | 4 -> c uniform in float4
    const double A = AB[c];
    const double B = AB[C_OUT + c];
    float4 v = ((float4*)out)[i4];
    v.x = (A * (double)v.x + B) > 0.0 ? 1.0f : 0.0f;
    v.y = (A * (double)v.y + B) > 0.0 ? 1.0f : 0.0f;
    v.z = (A * (double)v.z + B) > 0.0 ? 1.0f : 0.0f;
    v.w = (A * (double)v.w + B) > 0.0 ? 1.0f : 0.0f;
    ((float4*)out)[i4] = v;
}

// ---------------------------------------------------------------- finalize16
// Reads int16 S (16B/thread, NT), writes float 0/1 (32B/thread, NT).
__global__ __launch_bounds__(256) void finalize16(const short* __restrict__ S,
                                                  float* __restrict__ out,
                                                  const double* __restrict__ AB) {
    const unsigned t = blockIdx.x * 256 + threadIdx.x;    // 0 .. 3,211,263
    const unsigned e = t << 3;                             // element base, 8 per thread
    const int c = (int)((e / N_SP) & (C_OUT - 1));         // 3136 | 8 -> c uniform per chunk
    const double A = AB[c];
    const double B = AB[C_OUT + c];
    s16x8 v = __builtin_nontemporal_load((const s16x8*)(S + e));
    f32x4 o0, o1;
    o0.x = (A * (double)v[0] + B) > 0.0 ? 1.0f : 0.0f;
    o0.y = (A * (double)v[1] + B) > 0.0 ? 1.0f : 0.0f;
    o0.z = (A * (double)v[2] + B) > 0.0 ? 1.0f : 0.0f;
    o0.w = (A * (double)v[3] + B) > 0.0 ? 1.0f : 0.0f;
    o1.x = (A * (double)v[4] + B) > 0.0 ? 1.0f : 0.0f;
    o1.y = (A * (double)v[5] + B) > 0.0 ? 1.0f : 0.0f;
    o1.z = (A * (double)v[6] + B) > 0.0 ? 1.0f : 0.0f;
    o1.w = (A * (double)v[7] + B) > 0.0 ? 1.0f : 0.0f;
    __builtin_nontemporal_store(o0, (f32x4*)(out + e));
    __builtin_nontemporal_store(o1, (f32x4*)(out + e + 4));
}

// ---------------------------------------------------------------- launch
extern "C" void kernel_launch(void* const* d_in, const int* in_sizes, int n_in,
                              void* d_out, int out_size, void* d_ws, size_t ws_size,
                              hipStream_t stream) {
    const float* x      = (const float*)d_in[0];
    const float* weight = (const float*)d_in[1];
    const float* bias   = (const float*)d_in[2];   (void)bias;  // cancels in BN
    const float* gamma  = (const float*)d_in[3];
    const float* beta   = (const float*)d_in[4];
    float* out = (float*)d_out;

    char* ws = (char*)d_ws;
    double* alpha = (double*)(ws + 4096);       // [256]
    double* AB    = (double*)(ws + 8192);       // [512]
    char*   A_pack = (char*)(ws + 16384);       // 589,824 B fragment-ordered signs
    int2*   partials = (int2*)(ws + (1 << 20)); // 256*1792*8 = 3.67 MB (ends < 5 MB)
    char*   xsT   = (char*)(ws + (5 << 20));    // 30,408,704 B -> ends < 36 MB
    const bool use16 = ws_size >= S16_OFF + S16_BYTES;
    short*  s16 = use16 ? (short*)(ws + S16_OFF) : (short*)0;   // 51,380,224 B

    prep_and_transpose<<<1824, 256, 0, stream>>>(x, xsT, weight, A_pack, alpha);
    conv_mfma<<<dim3(NBLK), 512, 0, stream>>>(xsT, A_pack, out, s16, partials);
    stats_consts<<<C_OUT, 256, 0, stream>>>(partials, alpha, gamma, beta, AB);
    if (use16)
        finalize16<<<12544, 256, 0, stream>>>(s16, out, AB);
    else
        finalize<<<(out_size / 4) / 256, 256, 0, stream>>>(out, AB);
}